// Round 5
// baseline (112.041 us; speedup 1.0000x reference)
//
#include <hip/hip_runtime.h>
#include <math.h>

#define B 8
#define L 8192
#define H 1024
#define SCALE 0.03125f   // 1/sqrt(1024)

#define MAX_N 160        // >= 129 cantor keys
#define KPB   64         // colsum blocks per batch
#define ROWSC (L / KPB)  // 128 rows per colsum block
#define NPART (2 * KPB)  // partial rows per batch (even/odd row parity)

// ws layout (float offsets):
//   OFF_OUTS: hil_out (B*H) then can_out (B*H)
//   OFF_PART: partials (NPART*B*H)
//   OFF_CNT : B ints (completion counters, zeroed per launch)
#define OFF_OUTS 0
#define OFF_PART (2 * B * H)
#define OFF_CNT  (OFF_PART + NPART * B * H)

__device__ inline void d2xy_dev(int n, int d, int* px, int* py) {
    int x = 0, y = 0;
    for (int s = 1; s < n; s *= 2) {
        int rx = 1 & (d / 2);
        int ry = 1 & (d ^ rx);
        if (ry == 0) {
            if (rx == 1) { x = s - 1 - x; y = s - 1 - y; }
            int t = x; x = y; y = t;
        }
        x += s * rx; y += s * ry;
        d /= 4;
    }
    *px = x; *py = y;
}

__device__ inline int xy2d_dev(int n, int x, int y) {
    int d = 0;
    for (int s = n / 2; s > 0; s /= 2) {
        int rx = ((x & s) > 0) ? 1 : 0;
        int ry = ((y & s) > 0) ? 1 : 0;
        d += s * s * ((3 * rx) ^ ry);
        if (ry == 0) {
            if (rx == 1) { x = s - 1 - x; y = s - 1 - y; }
            int t = x; x = y; y = t;
        }
    }
    return d;
}

// Blocks 0..15: fused sparse attention (set = bid>>3, b = bid&7).
// Blocks 16..527: colsum partial over a 128-row slice of v (no LDS).
// Completion: per-batch counter; 66th contributor does the final combine.
__global__ __launch_bounds__(512)
void mega_kernel(const float* __restrict__ q, const float* __restrict__ k,
                 const float* __restrict__ v, const int* __restrict__ qidx_p,
                 const float* __restrict__ pw, float* __restrict__ ws_f,
                 int* __restrict__ cnt, float* __restrict__ out) {
    int bid = blockIdx.x;
    int tid = threadIdx.x;
    int myb;
    __shared__ int last_sh;

    if (bid < 16) {
        // ---------------- fused sparse attention ----------------
        int set = bid >> 3;   // 0 = hilbert, 1 = cantor
        int b   = bid & 7;
        myb = b;

        __shared__ float qs[H];
        __shared__ float sc[MAX_N];
        __shared__ float probs[MAX_N];
        __shared__ int   idx[MAX_N];
        __shared__ int   n_sh;
        __shared__ float sinv_sh;

        if (tid < H / 4)
            ((float4*)qs)[tid] = ((const float4*)(q + (size_t)b * H))[tid];

        if (set == 1) {
            // Cantor: closed-form per-lane walk of the 7-bit interval path.
            // Final positions are m/3^7; idx = m*8191/2187 is never within
            // 4.6e-4 of an integer -> truncation matches numpy; all distinct.
            if (tid < 129) {
                double l = (tid == 128) ? 1.0 : 0.0;
                if (tid < 128) {
                    double gap = 1.0;
                    #pragma unroll
                    for (int bit = 6; bit >= 0; --bit) {
                        double third = gap / 3.0;
                        if ((tid >> bit) & 1) { l += third; gap -= third; }
                        else                  { gap = third; }
                    }
                }
                idx[tid] = (int)(l * (double)(L - 1));
            }
            if (tid == 0) n_sh = 129;
        } else {
            // Hilbert: 49 candidates on wave 0, ballot-compact (order is
            // irrelevant: softmax+sum is permutation-invariant).
            if (tid < 64) {
                int center = qidx_p[0];
                if (center > 9999) center = 9999;
                if (center < 0) center = 0;
                int cx, cy;
                d2xy_dev(128, center, &cx, &cy);
                int val = -1;
                if (tid < 49) {
                    int x = cx + tid / 7 - 3, y = cy + tid % 7 - 3;
                    if (x >= 0 && x < 128 && y >= 0 && y < 128) {
                        int i = xy2d_dev(128, x, y);
                        if (i < L) val = i;
                    }
                }
                unsigned long long ball = __ballot(val >= 0);
                int pos = __popcll(ball & ((1ull << tid) - 1));
                if (val >= 0) idx[pos] = val;
                if (tid == 0) n_sh = __popcll(ball);
            }
        }
        __syncthreads();
        int n = n_sh;

        // scores: wave per key (8 waves)
        int wid = tid >> 6, lane = tid & 63;
        for (int j = wid; j < n; j += 8) {
            const float4* k4 =
                (const float4*)(k + ((size_t)b * L + (size_t)idx[j]) * H);
            float p = 0.f;
            #pragma unroll
            for (int i = 0; i < H / 256; i++) {
                float4 a = ((float4*)qs)[lane + i * 64];
                float4 c = k4[lane + i * 64];
                p += a.x * c.x + a.y * c.y + a.z * c.z + a.w * c.w;
            }
            #pragma unroll
            for (int off = 32; off; off >>= 1) p += __shfl_down(p, off);
            if (lane == 0) sc[j] = p * SCALE;
        }
        __syncthreads();

        // softmax on wave 0
        if (wid == 0) {
            float m = -1e30f;
            for (int j = lane; j < n; j += 64) m = fmaxf(m, sc[j]);
            #pragma unroll
            for (int mask = 32; mask; mask >>= 1) m = fmaxf(m, __shfl_xor(m, mask));
            float s = 0.f;
            for (int j = lane; j < n; j += 64) {
                float e = expf(sc[j] - m);
                probs[j] = e;
                s += e;
            }
            #pragma unroll
            for (int mask = 32; mask; mask >>= 1) s += __shfl_xor(s, mask);
            if (lane == 0) sinv_sh = 1.f / s;
        }
        __syncthreads();

        // PV: thread owns float2 column pair (2*tid, 2*tid+1)
        float ax = 0.f, ay = 0.f;
        #pragma unroll 4
        for (int j = 0; j < n; j++) {
            float p = probs[j];
            const float2 x =
                *(const float2*)(v + ((size_t)b * L + (size_t)idx[j]) * H + 2 * tid);
            ax += p * x.x; ay += p * x.y;
        }
        float sinv = sinv_sh;
        ((float2*)(ws_f + OFF_OUTS + ((size_t)set * B + b) * H))[tid] =
            make_float2(ax * sinv, ay * sinv);

    } else {
        // ---------------- colsum partial (dragon mean), no LDS ----------------
        int cb = bid - 16;
        int kp = cb >> 3, b = cb & 7;
        myb = b;
        int c4 = tid & 255;   // float4 column
        int r2 = tid >> 8;    // row parity 0/1

        const float4* base =
            (const float4*)(v + ((size_t)b * L + (size_t)kp * ROWSC) * H);
        float4 acc = make_float4(0.f, 0.f, 0.f, 0.f);
        #pragma unroll 4
        for (int rr = r2; rr < ROWSC; rr += 2) {
            float4 x = base[(size_t)rr * (H / 4) + c4];
            acc.x += x.x; acc.y += x.y; acc.z += x.z; acc.w += x.w;
        }
        ((float4*)(ws_f + OFF_PART + (((size_t)(kp * 2 + r2)) * B + b) * H))[c4] = acc;
    }

    // ---------------- completion protocol (device-scope) ----------------
    __syncthreads();                       // drain this block's global stores
    if (tid == 0) {
        __threadfence();                   // agent release: L2 writeback
        int old = __hip_atomic_fetch_add(&cnt[myb], 1, __ATOMIC_ACQ_REL,
                                         __HIP_MEMORY_SCOPE_AGENT);
        last_sh = (old == KPB + 2 - 1);
    }
    __syncthreads();
    if (last_sh) {
        __threadfence();                   // acquire: invalidate stale L1/L2
        if (tid < 256) {
            float w0 = pw[0], w1 = pw[1], w2 = pw[2];
            float m  = fmaxf(w0, fmaxf(w1, w2));
            float e0 = expf(w0 - m), e1 = expf(w1 - m), e2 = expf(w2 - m);
            float invs = 1.f / (e0 + e1 + e2);
            int b = myb;

            float4 s = make_float4(0.f, 0.f, 0.f, 0.f);
            for (int p2 = 0; p2 < NPART; p2++) {   // fixed order -> deterministic
                float4 x = ((const float4*)(ws_f + OFF_PART +
                                            ((size_t)p2 * B + b) * H))[tid];
                s.x += x.x; s.y += x.y; s.z += x.z; s.w += x.w;
            }
            float4 hil = ((const float4*)(ws_f + OFF_OUTS + (size_t)b * H))[tid];
            float4 can = ((const float4*)(ws_f + OFF_OUTS +
                                          ((size_t)B + b) * H))[tid];
            const float il = 1.0f / (float)L;  // dragon weights exactly 0 -> uniform
            float4 o;
            o.x = (e0 * hil.x + e1 * can.x + e2 * (s.x * il)) * invs;
            o.y = (e0 * hil.y + e1 * can.y + e2 * (s.y * il)) * invs;
            o.z = (e0 * hil.z + e1 * can.z + e2 * (s.z * il)) * invs;
            o.w = (e0 * hil.w + e1 * can.w + e2 * (s.w * il)) * invs;
            ((float4*)(out + (size_t)b * H))[tid] = o;
        }
    }
}

extern "C" void kernel_launch(void* const* d_in, const int* in_sizes, int n_in,
                              void* d_out, int out_size, void* d_ws, size_t ws_size,
                              hipStream_t stream) {
    const float* q  = (const float*)d_in[0];
    const float* k  = (const float*)d_in[1];
    const float* v  = (const float*)d_in[2];
    const float* pw = (const float*)d_in[3];
    const int* qidx = (const int*)d_in[4];

    float* ws_f = (float*)d_ws;
    int*   cnt  = (int*)((char*)d_ws + (size_t)OFF_CNT * 4);

    hipMemsetAsync(cnt, 0, B * sizeof(int), stream);
    mega_kernel<<<16 + KPB * B, 512, 0, stream>>>(q, k, v, qidx, pw, ws_f, cnt,
                                                  (float*)d_out);
}

// Round 6
// 73.616 us; speedup vs baseline: 1.5220x; 1.5220x over previous
//
#include <hip/hip_runtime.h>
#include <math.h>

#define B 8
#define L 8192
#define H 1024
#define SCALE 0.03125f   // 1/sqrt(1024)

#define MAX_N 160        // >= 129 cantor keys
#define KPB   64         // colsum blocks per batch
#define ROWSC (L / KPB)  // 128 rows per colsum block
#define NPART (2 * KPB)  // partial rows per batch (even/odd row parity)

// ws layout (float offsets):
//   OFF_OUTS: hil_out (B*H) then can_out (B*H)
//   OFF_PART: partials (NPART*B*H), layout [p][b][h]
#define OFF_OUTS 0
#define OFF_PART (2 * B * H)

__device__ inline void d2xy_dev(int n, int d, int* px, int* py) {
    int x = 0, y = 0;
    for (int s = 1; s < n; s *= 2) {
        int rx = 1 & (d / 2);
        int ry = 1 & (d ^ rx);
        if (ry == 0) {
            if (rx == 1) { x = s - 1 - x; y = s - 1 - y; }
            int t = x; x = y; y = t;
        }
        x += s * rx; y += s * ry;
        d /= 4;
    }
    *px = x; *py = y;
}

__device__ inline int xy2d_dev(int n, int x, int y) {
    int d = 0;
    for (int s = n / 2; s > 0; s /= 2) {
        int rx = ((x & s) > 0) ? 1 : 0;
        int ry = ((y & s) > 0) ? 1 : 0;
        d += s * s * ((3 * rx) ^ ry);
        if (ry == 0) {
            if (rx == 1) { x = s - 1 - x; y = s - 1 - y; }
            int t = x; x = y; y = t;
        }
    }
    return d;
}

// Blocks 0..15: fused sparse attention (set = bid>>3, b = bid&7).
// Blocks 16..527: colsum partial over a 128-row slice of v (no LDS, no sync).
// 528 blocks x 512 threads -> fully resident in one scheduling round.
__global__ __launch_bounds__(512)
void mega_kernel(const float* __restrict__ q, const float* __restrict__ k,
                 const float* __restrict__ v, const int* __restrict__ qidx_p,
                 float* __restrict__ ws_f) {
    int bid = blockIdx.x;
    int tid = threadIdx.x;

    if (bid >= 16) {
        // ---------------- colsum partial (dragon mean) ----------------
        int cb = bid - 16;
        int kp = cb >> 3, b = cb & 7;
        int c4 = tid & 255;   // float4 column
        int r2 = tid >> 8;    // row parity 0/1

        const float4* base =
            (const float4*)(v + ((size_t)b * L + (size_t)kp * ROWSC) * H);
        float4 acc = make_float4(0.f, 0.f, 0.f, 0.f);
        #pragma unroll 4
        for (int rr = r2; rr < ROWSC; rr += 2) {
            float4 x = base[(size_t)rr * (H / 4) + c4];
            acc.x += x.x; acc.y += x.y; acc.z += x.z; acc.w += x.w;
        }
        ((float4*)(ws_f + OFF_PART + (((size_t)(kp * 2 + r2)) * B + b) * H))[c4] = acc;
        return;
    }

    // ---------------- fused sparse attention ----------------
    int set = bid >> 3;   // 0 = hilbert, 1 = cantor
    int b   = bid & 7;

    __shared__ float qs[H];
    __shared__ float sc[MAX_N];
    __shared__ float probs[MAX_N];
    __shared__ int   idx[MAX_N];
    __shared__ int   n_sh;
    __shared__ float sinv_sh;

    if (tid < H / 4)
        ((float4*)qs)[tid] = ((const float4*)(q + (size_t)b * H))[tid];

    if (set == 1) {
        // Cantor: closed-form per-lane walk of the 7-bit interval path.
        // Final positions are m/3^7; idx = m*8191/2187 is never within
        // 4.6e-4 of an integer -> truncation matches numpy; all distinct.
        if (tid < 129) {
            double l = (tid == 128) ? 1.0 : 0.0;
            if (tid < 128) {
                double gap = 1.0;
                #pragma unroll
                for (int bit = 6; bit >= 0; --bit) {
                    double third = gap / 3.0;
                    if ((tid >> bit) & 1) { l += third; gap -= third; }
                    else                  { gap = third; }
                }
            }
            idx[tid] = (int)(l * (double)(L - 1));
        }
        if (tid == 0) n_sh = 129;
    } else {
        // Hilbert: 49 candidates on wave 0, ballot-compact (order is
        // irrelevant: softmax+sum is permutation-invariant).
        if (tid < 64) {
            int center = qidx_p[0];
            if (center > 9999) center = 9999;
            if (center < 0) center = 0;
            int cx, cy;
            d2xy_dev(128, center, &cx, &cy);
            int val = -1;
            if (tid < 49) {
                int x = cx + tid / 7 - 3, y = cy + tid % 7 - 3;
                if (x >= 0 && x < 128 && y >= 0 && y < 128) {
                    int i = xy2d_dev(128, x, y);
                    if (i < L) val = i;
                }
            }
            unsigned long long ball = __ballot(val >= 0);
            int pos = __popcll(ball & ((1ull << tid) - 1));
            if (val >= 0) idx[pos] = val;
            if (tid == 0) n_sh = __popcll(ball);
        }
    }
    __syncthreads();
    int n = n_sh;

    // scores: wave per key (8 waves)
    int wid = tid >> 6, lane = tid & 63;
    for (int j = wid; j < n; j += 8) {
        const float4* k4 =
            (const float4*)(k + ((size_t)b * L + (size_t)idx[j]) * H);
        float p = 0.f;
        #pragma unroll
        for (int i = 0; i < H / 256; i++) {
            float4 a = ((float4*)qs)[lane + i * 64];
            float4 c = k4[lane + i * 64];
            p += a.x * c.x + a.y * c.y + a.z * c.z + a.w * c.w;
        }
        #pragma unroll
        for (int off = 32; off; off >>= 1) p += __shfl_down(p, off);
        if (lane == 0) sc[j] = p * SCALE;
    }
    __syncthreads();

    // softmax on wave 0
    if (wid == 0) {
        float m = -1e30f;
        for (int j = lane; j < n; j += 64) m = fmaxf(m, sc[j]);
        #pragma unroll
        for (int mask = 32; mask; mask >>= 1) m = fmaxf(m, __shfl_xor(m, mask));
        float s = 0.f;
        for (int j = lane; j < n; j += 64) {
            float e = expf(sc[j] - m);
            probs[j] = e;
            s += e;
        }
        #pragma unroll
        for (int mask = 32; mask; mask >>= 1) s += __shfl_xor(s, mask);
        if (lane == 0) sinv_sh = 1.f / s;
    }
    __syncthreads();

    // PV: thread owns float2 column pair (2*tid, 2*tid+1)
    float ax = 0.f, ay = 0.f;
    #pragma unroll 4
    for (int j = 0; j < n; j++) {
        float p = probs[j];
        const float2 x =
            *(const float2*)(v + ((size_t)b * L + (size_t)idx[j]) * H + 2 * tid);
        ax += p * x.x; ay += p * x.y;
    }
    float sinv = sinv_sh;
    ((float2*)(ws_f + OFF_OUTS + ((size_t)set * B + b) * H))[tid] =
        make_float2(ax * sinv, ay * sinv);
}

// 8 blocks x 256 threads: thread owns one float4 column of one batch.
__global__ __launch_bounds__(256)
void combine_kernel(const float* __restrict__ pw, const float* __restrict__ ws_f,
                    float* __restrict__ out) {
    int b = blockIdx.x;
    int c4 = threadIdx.x;
    float w0 = pw[0], w1 = pw[1], w2 = pw[2];
    float m  = fmaxf(w0, fmaxf(w1, w2));
    float e0 = expf(w0 - m), e1 = expf(w1 - m), e2 = expf(w2 - m);
    float invs = 1.f / (e0 + e1 + e2);

    float4 s = make_float4(0.f, 0.f, 0.f, 0.f);
    #pragma unroll 8
    for (int p2 = 0; p2 < NPART; p2++) {   // fixed order -> deterministic
        float4 x = ((const float4*)(ws_f + OFF_PART +
                                    ((size_t)p2 * B + b) * H))[c4];
        s.x += x.x; s.y += x.y; s.z += x.z; s.w += x.w;
    }
    float4 hil = ((const float4*)(ws_f + OFF_OUTS + (size_t)b * H))[c4];
    float4 can = ((const float4*)(ws_f + OFF_OUTS + ((size_t)B + b) * H))[c4];
    const float il = 1.0f / (float)L;  // dragon weights exactly 0 -> uniform attn
    float4 o;
    o.x = (e0 * hil.x + e1 * can.x + e2 * (s.x * il)) * invs;
    o.y = (e0 * hil.y + e1 * can.y + e2 * (s.y * il)) * invs;
    o.z = (e0 * hil.z + e1 * can.z + e2 * (s.z * il)) * invs;
    o.w = (e0 * hil.w + e1 * can.w + e2 * (s.w * il)) * invs;
    ((float4*)(out + (size_t)b * H))[c4] = o;
}

extern "C" void kernel_launch(void* const* d_in, const int* in_sizes, int n_in,
                              void* d_out, int out_size, void* d_ws, size_t ws_size,
                              hipStream_t stream) {
    const float* q  = (const float*)d_in[0];
    const float* k  = (const float*)d_in[1];
    const float* v  = (const float*)d_in[2];
    const float* pw = (const float*)d_in[3];
    const int* qidx = (const int*)d_in[4];

    float* ws_f = (float*)d_ws;

    mega_kernel<<<16 + KPB * B, 512, 0, stream>>>(q, k, v, qidx, ws_f);
    combine_kernel<<<B, 256, 0, stream>>>(pw, ws_f, (float*)d_out);
}